// Round 5
// baseline (433.035 us; speedup 1.0000x reference)
//
#include <hip/hip_runtime.h>
#include <math.h>

#define NPG 1000
#define KTOP 500
#define C 64
#define EPG 16000   // edges per graph = NPG * DEG
#define BPG 63      // gather blocks per graph: ceil(250/4), 4 bases/block, 4 nodes/base-wave

__device__ __forceinline__ float readlane_f(float v, int l) {
    return __uint_as_float(__builtin_amdgcn_readlane(__float_as_uint(v), (unsigned)l));
}
__device__ __forceinline__ int readlane_i(int v, int l) {
    return (int)__builtin_amdgcn_readlane((unsigned)v, (unsigned)l);
}

// ---------------- per-graph degree count + scan -> deg, dinv, off ----------------
// Only reads the dst half of the edge list. Unblocks gemm's dinv epilogue so the
// csr scatter and the gemm can run concurrently in the next (fused) dispatch.
__global__ __launch_bounds__(256) void count_k(const int* __restrict__ ei, int E,
                                               int* __restrict__ deg,
                                               float* __restrict__ dinv,
                                               int* __restrict__ off) {
    int g = blockIdx.x, t = threadIdx.x;
    __shared__ int cnt[NPG];
    __shared__ int soff[NPG];
    __shared__ int red[256];
    const int gbase = g * NPG;
    const int ebase = g * EPG;
    const int* __restrict__ dstp = ei + E + ebase;

    for (int i = t; i < NPG; i += 256) cnt[i] = 0;
    __syncthreads();
    for (int i = t; i < EPG; i += 256) atomicAdd(&cnt[dstp[i] - gbase], 1);
    __syncthreads();
    // exclusive scan over 1000 counts (4/thread + Hillis-Steele on 256)
    int base = t * 4;
    int v0 = 0, v1 = 0, v2 = 0, v3 = 0;
    if (base + 0 < NPG) v0 = cnt[base + 0];
    if (base + 1 < NPG) v1 = cnt[base + 1];
    if (base + 2 < NPG) v2 = cnt[base + 2];
    if (base + 3 < NPG) v3 = cnt[base + 3];
    int s = v0 + v1 + v2 + v3;
    red[t] = s;
    __syncthreads();
    for (int o = 1; o < 256; o <<= 1) {
        int xx = (t >= o) ? red[t - o] : 0;
        __syncthreads();
        red[t] += xx;
        __syncthreads();
    }
    int p = red[t] - s;
    if (base + 0 < NPG) { soff[base + 0] = p; p += v0; }
    if (base + 1 < NPG) { soff[base + 1] = p; p += v1; }
    if (base + 2 < NPG) { soff[base + 2] = p; p += v2; }
    if (base + 3 < NPG) { soff[base + 3] = p; p += v3; }
    __syncthreads();
    for (int i = t; i < NPG; i += 256) {
        int d = cnt[i];
        deg[gbase + i] = d;
        dinv[gbase + i] = 1.0f / sqrtf((float)(d + 1));
        off[gbase + i] = ebase + soff[i];
    }
}

// ---------------- fused dispatch: csr scatter (blocks [0,B)) || gemm (blocks [B,...)) ----
// Scatter: cursors reloaded from off (no re-count); all scatter traffic in LDS, csr
// dumped coalesced. Gemm: h2 = (x @ W) * dinv[row], register-tiled 2 rows/thread,
// W staged in LDS. Independent workloads -> co-resident blocks overlap the scatter's
// latency under the gemm's LDS/VALU work.
__global__ __launch_bounds__(256) void scatter_gemm_k(const int* __restrict__ ei, int E,
                                                      const int* __restrict__ off,
                                                      int* __restrict__ csr,
                                                      const float* __restrict__ x,
                                                      const float* __restrict__ W,
                                                      const float* __restrict__ dinv,
                                                      float* __restrict__ h2,
                                                      int N, int B) {
    __shared__ char smem[36000] __attribute__((aligned(16)));
    int t = threadIdx.x;
    if (blockIdx.x < (unsigned)B) {
        // ---- csr scatter ----
        int* cnt = (int*)smem;                         // 4000 B: cursors
        unsigned short* lcsr = (unsigned short*)(smem + 4000);  // 32000 B
        int g = blockIdx.x;
        const int gbase = g * NPG;
        const int ebase = g * EPG;
        const int* __restrict__ srcp = ei + ebase;
        const int* __restrict__ dstp = ei + E + ebase;
        for (int i = t; i < NPG; i += 256) cnt[i] = off[gbase + i] - ebase;
        __syncthreads();
        for (int i = t; i < EPG; i += 256) {
            int d = dstp[i] - gbase;
            int pos = atomicAdd(&cnt[d], 1);
            lcsr[pos] = (unsigned short)(srcp[i] - gbase);
        }
        __syncthreads();
        int4* co = (int4*)(csr + ebase);
        for (int i = t; i < EPG / 4; i += 256) {
            int4 vv;
            vv.x = gbase + (int)lcsr[i * 4 + 0];
            vv.y = gbase + (int)lcsr[i * 4 + 1];
            vv.z = gbase + (int)lcsr[i * 4 + 2];
            vv.w = gbase + (int)lcsr[i * 4 + 3];
            co[i] = vv;
        }
    } else {
        // ---- gemm ----
        float* sW = (float*)smem;                      // 16384 B
        for (int i = t; i < C * C / 4; i += 256) ((float4*)sW)[i] = ((const float4*)W)[i];
        __syncthreads();
        int gb = blockIdx.x - B;
        int r0 = gb * 512 + t;
        int r1 = r0 + 256;
        if (r0 >= N) return;
        bool has1 = (r1 < N);
        const float4* x0 = (const float4*)(x + (size_t)r0 * C);
        const float4* x1 = (const float4*)(x + (size_t)(has1 ? r1 : r0) * C);
        float acc0[C], acc1[C];
#pragma unroll
        for (int i = 0; i < C; ++i) { acc0[i] = 0.f; acc1[i] = 0.f; }
        float4 a0 = x0[0], a1 = x1[0];
        for (int k4 = 0; k4 < 16; ++k4) {
            float4 b0, b1;
            if (k4 < 15) { b0 = x0[k4 + 1]; b1 = x1[k4 + 1]; }
            const float4* wr = (const float4*)(sW + k4 * 4 * C);
            const float* a0f = (const float*)&a0;
            const float* a1f = (const float*)&a1;
#pragma unroll
            for (int c4 = 0; c4 < 16; ++c4) {
                float4 w[4];
                w[0] = wr[c4]; w[1] = wr[16 + c4]; w[2] = wr[32 + c4]; w[3] = wr[48 + c4];
                const float* wf = (const float*)w;
#pragma unroll
                for (int j = 0; j < 4; ++j) {
                    float s0 = acc0[c4 * 4 + j], s1 = acc1[c4 * 4 + j];
#pragma unroll
                    for (int kk = 0; kk < 4; ++kk) {
                        float wv = wf[kk * 4 + j];
                        s0 = fmaf(a0f[kk], wv, s0);
                        s1 = fmaf(a1f[kk], wv, s1);
                    }
                    acc0[c4 * 4 + j] = s0; acc1[c4 * 4 + j] = s1;
                }
            }
            a0 = b0; a1 = b1;
        }
        float dv0 = dinv[r0];
        float dv1 = has1 ? dinv[r1] : 0.f;
#pragma unroll
        for (int i = 0; i < C; ++i) { acc0[i] *= dv0; acc1[i] *= dv1; }
        float4* h0 = (float4*)(h2 + (size_t)r0 * C);
#pragma unroll
        for (int q = 0; q < 16; ++q) h0[q] = ((float4*)acc0)[q];
        if (has1) {
            float4* h1 = (float4*)(h2 + (size_t)r1 * C);
#pragma unroll
            for (int q = 0; q < 16; ++q) h1[q] = ((float4*)acc1)[q];
        }
    }
}

// ---------------- gather aggregation: 4 nodes per wave, lane = channel (unchanged) ------
__global__ __launch_bounds__(256) void gather_k(const int* __restrict__ csr,
                                                const int* __restrict__ off,
                                                const int* __restrict__ deg,
                                                const float* __restrict__ h2,
                                                const float* __restrict__ dinv,
                                                const float* __restrict__ bias,
                                                float* __restrict__ out2,
                                                float* __restrict__ cen_sum,
                                                int N, int B) {
    __shared__ float cenacc[C];
    int blk = blockIdx.x;
    int wave = threadIdx.x >> 6;
    int lane = threadIdx.x & 63;
    int t = threadIdx.x;
    int g, blkin;
    if ((B & 7) == 0) {                    // XCD swizzle: whole graph on one XCD
        int xcd = blk & 7, slot = blk >> 3;
        g = (slot / BPG) * 8 + xcd;
        blkin = slot % BPG;
    } else {
        g = blk / BPG;
        blkin = blk % BPG;
    }
    if (t < C) cenacc[t] = 0.f;
    __syncthreads();

    int base = blkin * 4 + wave;
    bool active = (base < NPG / 4);
    if (active) {
        int nA = g * NPG + base;
        int nB = nA + 250, nC = nA + 500, nD = nA + 750;
        int oA = off[nA], oB = off[nB], oC = off[nC], oD = off[nD];
        int dA = deg[nA], dB = deg[nB], dC = deg[nC], dD = deg[nD];
        float diA = dinv[nA], diB = dinv[nB], diC = dinv[nC], diD = dinv[nD];
        float hA = h2[(size_t)nA * C + lane];
        float hB = h2[(size_t)nB * C + lane];
        float hC = h2[(size_t)nC * C + lane];
        float hD = h2[(size_t)nD * C + lane];
        float bv = bias[lane];
        int svA = (lane < dA) ? csr[oA + lane] : nA;
        int svB = (lane < dB) ? csr[oB + lane] : nB;
        int svC = (lane < dC) ? csr[oC + lane] : nC;
        int svD = (lane < dD) ? csr[oD + lane] : nD;
        int jmA = dA < 64 ? dA : 64;
        int jmB = dB < 64 ? dB : 64;
        int jmC = dC < 64 ? dC : 64;
        int jmD = dD < 64 ? dD : 64;
        int rA = (jmA + 3) & ~3, rB = (jmB + 3) & ~3;
        int rC = (jmC + 3) & ~3, rD = (jmD + 3) & ~3;
        int m0 = rA > rB ? rA : rB;
        int m1 = rC > rD ? rC : rD;
        int mmax = m0 > m1 ? m0 : m1;
        float aA = 0.f, aB = 0.f, aC = 0.f, aD = 0.f;
        for (int j = 0; j < mmax; j += 4) {
            if (j < rA) {
                int s0 = readlane_i(svA, j + 0), s1 = readlane_i(svA, j + 1);
                int s2 = readlane_i(svA, j + 2), s3 = readlane_i(svA, j + 3);
                float v0 = h2[(size_t)s0 * C + lane];
                float v1 = h2[(size_t)s1 * C + lane];
                float v2 = h2[(size_t)s2 * C + lane];
                float v3 = h2[(size_t)s3 * C + lane];
                aA += (v0 + v1) + (v2 + v3);
            }
            if (j < rB) {
                int s0 = readlane_i(svB, j + 0), s1 = readlane_i(svB, j + 1);
                int s2 = readlane_i(svB, j + 2), s3 = readlane_i(svB, j + 3);
                float v0 = h2[(size_t)s0 * C + lane];
                float v1 = h2[(size_t)s1 * C + lane];
                float v2 = h2[(size_t)s2 * C + lane];
                float v3 = h2[(size_t)s3 * C + lane];
                aB += (v0 + v1) + (v2 + v3);
            }
            if (j < rC) {
                int s0 = readlane_i(svC, j + 0), s1 = readlane_i(svC, j + 1);
                int s2 = readlane_i(svC, j + 2), s3 = readlane_i(svC, j + 3);
                float v0 = h2[(size_t)s0 * C + lane];
                float v1 = h2[(size_t)s1 * C + lane];
                float v2 = h2[(size_t)s2 * C + lane];
                float v3 = h2[(size_t)s3 * C + lane];
                aC += (v0 + v1) + (v2 + v3);
            }
            if (j < rD) {
                int s0 = readlane_i(svD, j + 0), s1 = readlane_i(svD, j + 1);
                int s2 = readlane_i(svD, j + 2), s3 = readlane_i(svD, j + 3);
                float v0 = h2[(size_t)s0 * C + lane];
                float v1 = h2[(size_t)s1 * C + lane];
                float v2 = h2[(size_t)s2 * C + lane];
                float v3 = h2[(size_t)s3 * C + lane];
                aD += (v0 + v1) + (v2 + v3);
            }
        }
        for (int j = 64; j < dA; ++j) aA += h2[(size_t)csr[oA + j] * C + lane];
        for (int j = 64; j < dB; ++j) aB += h2[(size_t)csr[oB + j] * C + lane];
        for (int j = 64; j < dC; ++j) aC += h2[(size_t)csr[oC + j] * C + lane];
        for (int j = 64; j < dD; ++j) aD += h2[(size_t)csr[oD + j] * C + lane];
        float cA = 1.0f - (float)(rA - jmA);
        float cB = 1.0f - (float)(rB - jmB);
        float cC = 1.0f - (float)(rC - jmC);
        float cD = 1.0f - (float)(rD - jmD);
        float resA = fmaf(diA, fmaf(cA, hA, aA), bv);
        float resB = fmaf(diB, fmaf(cB, hB, aB), bv);
        float resC = fmaf(diC, fmaf(cC, hC, aC), bv);
        float resD = fmaf(diD, fmaf(cD, hD, aD), bv);
        out2[(size_t)nA * C + lane] = resA;
        out2[(size_t)nB * C + lane] = resB;
        out2[(size_t)nC * C + lane] = resC;
        out2[(size_t)nD * C + lane] = resD;
        float csum = (resA + resB) + (resC + resD);
        atomicAdd(&cenacc[lane], csum);
    }
    __syncthreads();
    if (t < C) atomicAdd(&cen_sum[(size_t)g * C + t], cenacc[t]);
}

// ---------------- per-graph tail: centroid + score + softmax-KL + sort + top-K ----------
// Edge re-index moved OUT (device-wide kernel); mapping written to global coalesced.
// Score phase: 4 rows per wave per round (independent load/reduce chains).
__global__ __launch_bounds__(1024) void post1_k(const float* __restrict__ out2,
                                                const float* __restrict__ cen_sum,
                                                int* __restrict__ mapping,
                                                float* __restrict__ o_xnew,
                                                float* __restrict__ o_batch,
                                                float* __restrict__ o_perm,
                                                float* __restrict__ o_kl,
                                                float* __restrict__ o_ind) {
    __shared__ float ss[NPG];
    __shared__ float red[1024];
    __shared__ unsigned long long kk[1024];
    __shared__ int   map[NPG];
    __shared__ float cenl[C];
    __shared__ float cns;
    int g = blockIdx.x, t = threadIdx.x;
    int wave = t >> 6, lane = t & 63;
    const int gbase = g * NPG;

    // centroid finalize
    if (t < C) cenl[t] = cen_sum[(size_t)g * C + t] * (1.0f / 1000.0f);
    __syncthreads();
    if (t < 64) {
        float m = cenl[t];
        float v = m * m;
        for (int o = 32; o > 0; o >>= 1) v += __shfl_down(v, o, 64);
        if (t == 0) cns = sqrtf(v);
    }
    __syncthreads();
    // score: 4 rows per wave per round, lane = channel
    float cv = cenl[lane];
    float cn = cns;
    for (int base = wave * 4; base < NPG; base += 64) {
        float a0 = out2[(size_t)(gbase + base + 0) * C + lane];
        float a1 = out2[(size_t)(gbase + base + 1) * C + lane];
        float a2 = out2[(size_t)(gbase + base + 2) * C + lane];
        float a3 = out2[(size_t)(gbase + base + 3) * C + lane];
        float n0 = a0 * cv, n1 = a1 * cv, n2 = a2 * cv, n3 = a3 * cv;
        float q0 = a0 * a0, q1 = a1 * a1, q2 = a2 * a2, q3 = a3 * a3;
        for (int o = 32; o > 0; o >>= 1) {
            n0 += __shfl_down(n0, o, 64); q0 += __shfl_down(q0, o, 64);
            n1 += __shfl_down(n1, o, 64); q1 += __shfl_down(q1, o, 64);
            n2 += __shfl_down(n2, o, 64); q2 += __shfl_down(q2, o, 64);
            n3 += __shfl_down(n3, o, 64); q3 += __shfl_down(q3, o, 64);
        }
        if (lane == 0) {
            ss[base + 0] = n0 / (sqrtf(q0) * cn + 1e-8f);
            ss[base + 1] = n1 / (sqrtf(q1) * cn + 1e-8f);
            ss[base + 2] = n2 / (sqrtf(q2) * cn + 1e-8f);
            ss[base + 3] = n3 / (sqrtf(q3) * cn + 1e-8f);
        }
    }
    __syncthreads();
    // softmax KL vs uniform
    float mx = -INFINITY;
    for (int i = t; i < NPG; i += 1024) mx = fmaxf(mx, ss[i]);
    red[t] = mx;
    __syncthreads();
    for (int w = 512; w > 0; w >>= 1) { if (t < w) red[t] = fmaxf(red[t], red[t + w]); __syncthreads(); }
    mx = red[0];
    __syncthreads();
    float se = 0.f;
    for (int i = t; i < NPG; i += 1024) se += expf(ss[i] - mx);
    red[t] = se;
    __syncthreads();
    for (int w = 512; w > 0; w >>= 1) { if (t < w) red[t] += red[t + w]; __syncthreads(); }
    float lse = logf(red[0]);
    __syncthreads();
    float kl = 0.f;
    const float ln_npg = 6.9077552790f;
    for (int i = t; i < NPG; i += 1024) {
        float lp = ss[i] - mx - lse;
        kl += expf(lp) * (lp + ln_npg);
    }
    red[t] = kl;
    __syncthreads();
    for (int w = 512; w > 0; w >>= 1) { if (t < w) red[t] += red[t + w]; __syncthreads(); }
    if (t == 0) o_kl[g] = red[0];
    // descending stable argsort via ascending (~flipped_score, idx) bitonic
    unsigned long long v;
    if (t < NPG) {
        unsigned u = __float_as_uint(ss[t]);
        u = (u & 0x80000000u) ? ~u : (u | 0x80000000u);
        v = ((unsigned long long)(~u) << 32) | (unsigned)t;
    } else {
        v = ~0ULL;
    }
    __syncthreads();
    kk[t] = v;
    __syncthreads();
    for (int k = 2; k <= 1024; k <<= 1) {
        for (int j = k >> 1; j > 0; j >>= 1) {
            int ixj = t ^ j;
            if (ixj > t) {
                unsigned long long a = kk[t], b2 = kk[ixj];
                bool up = ((t & k) == 0);
                if ((a > b2) == up) { kk[t] = b2; kk[ixj] = a; }
            }
            __syncthreads();
        }
    }
    // indices output + mapping init
    if (t < NPG) {
        int idx = (int)(kk[t] & 0xFFFFFFFFULL);
        o_ind[(size_t)g * NPG + t] = (float)idx;
        map[t] = -1;
    }
    __syncthreads();
    // top-K bookkeeping
    if (t < KTOP) {
        int node = (int)(kk[t] & 0xFFFFFFFFULL);
        map[node] = g * KTOP + t;
        o_perm[(size_t)g * KTOP + t] = (float)(gbase + node);
        o_batch[(size_t)g * KTOP + t] = (float)g;
    }
    __syncthreads();
    // mapping -> global (coalesced)
    if (t < NPG) mapping[gbase + t] = map[t];
    // x_new rows: wave per row (coalesced 256B read+write)
    for (int r = wave; r < KTOP; r += 16) {
        int node = (int)(kk[r] & 0xFFFFFFFFULL);
        float tn = tanhf(ss[node]);
        o_xnew[((size_t)g * KTOP + r) * C + lane] =
            out2[(size_t)(gbase + node) * C + lane] * tn;
    }
}

// ---------------- edge re-index + mask + attr (device-wide, x4 vectorized) ----------------
__global__ void edge_out_k(const int* __restrict__ ei, const float* __restrict__ eattr,
                           const int* __restrict__ mapping, float* __restrict__ o_newei,
                           float* __restrict__ o_eattr, float* __restrict__ o_mask, int E) {
    int e4 = blockIdx.x * 256 + threadIdx.x;
    int q = E >> 2;
    if (e4 < q) {
        int4 sidx = ((const int4*)ei)[e4];
        int4 didx = ((const int4*)ei)[q + e4];
        int a0 = mapping[sidx.x], a1 = mapping[sidx.y], a2 = mapping[sidx.z], a3 = mapping[sidx.w];
        int b0 = mapping[didx.x], b1 = mapping[didx.y], b2 = mapping[didx.z], b3 = mapping[didx.w];
        float4 f0 = { (float)a0, (float)a1, (float)a2, (float)a3 };
        float4 f1 = { (float)b0, (float)b1, (float)b2, (float)b3 };
        ((float4*)o_newei)[e4] = f0;
        ((float4*)o_newei)[q + e4] = f1;
        float4 at = ((const float4*)eattr)[e4];
        float4 mk, ea;
        mk.x = (a0 >= 0 && b0 >= 0) ? 1.0f : 0.0f;
        mk.y = (a1 >= 0 && b1 >= 0) ? 1.0f : 0.0f;
        mk.z = (a2 >= 0 && b2 >= 0) ? 1.0f : 0.0f;
        mk.w = (a3 >= 0 && b3 >= 0) ? 1.0f : 0.0f;
        ea.x = mk.x != 0.0f ? at.x : 0.0f;
        ea.y = mk.y != 0.0f ? at.y : 0.0f;
        ea.z = mk.z != 0.0f ? at.z : 0.0f;
        ea.w = mk.w != 0.0f ? at.w : 0.0f;
        ((float4*)o_mask)[e4] = mk;
        ((float4*)o_eattr)[e4] = ea;
    }
}

extern "C" void kernel_launch(void* const* d_in, const int* in_sizes, int n_in,
                              void* d_out, int out_size, void* d_ws, size_t ws_size,
                              hipStream_t stream) {
    (void)n_in; (void)out_size; (void)ws_size;
    const float* x     = (const float*)d_in[1];
    const int*   ei    = (const int*)d_in[2];
    const float* eattr = (const float*)d_in[3];
    const float* W     = (const float*)d_in[5];
    const float* bias  = (const float*)d_in[6];

    const int N  = in_sizes[1] / C;    // 256000
    const int E  = in_sizes[2] / 2;    // 4096000
    const int B  = N / NPG;            // 256
    const int BK = B * KTOP;           // 128000

    // workspace layout
    char* wsp = (char*)d_ws;
    float* out2    = (float*)wsp; wsp += (size_t)N * C * 4;   // 65.5 MB
    float* dinv    = (float*)wsp; wsp += (size_t)N * 4;
    int*   deg     = (int*)wsp;   wsp += (size_t)N * 4;
    int*   off     = (int*)wsp;   wsp += (size_t)N * 4;
    int*   mapping = (int*)wsp;   wsp += (size_t)N * 4;
    float* cen_sum = (float*)wsp; wsp += (size_t)B * C * 4;

    // output layout (flat f32, reference return order)
    float* out     = (float*)d_out;
    float* o_xnew  = out;                                   // BK*C
    float* o_newei = o_xnew + (size_t)BK * C;               // 2E
    float* o_eattr = o_newei + 2 * (size_t)E;               // E
    float* o_mask  = o_eattr + (size_t)E;                   // E
    float* o_batch = o_mask + (size_t)E;                    // BK
    float* o_perm  = o_batch + (size_t)BK;                  // BK
    float* o_kl    = o_perm + (size_t)BK;                   // B
    float* o_ind   = o_kl + (size_t)B;                      // B*NPG

    // scratch aliased onto d_out (dead before those outputs are written)
    float* h2buf = out;                // N*C floats (= o_xnew + o_newei region, exactly)
    int*   csr   = (int*)o_eattr;      // E ints

    hipMemsetAsync(cen_sum, 0, (size_t)B * C * 4, stream);

    count_k<<<B, 256, 0, stream>>>(ei, E, deg, dinv, off);
    scatter_gemm_k<<<B + (N + 511) / 512, 256, 0, stream>>>(ei, E, off, csr,
                                                            x, W, dinv, h2buf, N, B);
    gather_k<<<B * BPG, 256, 0, stream>>>(csr, off, deg, h2buf, dinv, bias, out2,
                                          cen_sum, N, B);
    post1_k<<<B, 1024, 0, stream>>>(out2, cen_sum, mapping,
                                    o_xnew, o_batch, o_perm, o_kl, o_ind);
    edge_out_k<<<(E / 4 + 255) / 256, 256, 0, stream>>>(ei, eattr, mapping,
                                                        o_newei, o_eattr, o_mask, E);
}

// Round 6
// 404.436 us; speedup vs baseline: 1.0707x; 1.0707x over previous
//
#include <hip/hip_runtime.h>
#include <math.h>

#define NPG 1000
#define KTOP 500
#define C 64
#define EPG 16000   // edges per graph = NPG * DEG
#define BPG 63      // gather blocks per graph: ceil(250/4), 4 bases/block, 4 nodes/base-wave

__device__ __forceinline__ int readlane_i(int v, int l) {
    return (int)__builtin_amdgcn_readlane((unsigned)v, (unsigned)l);
}

// ---------------- fused per-graph CSR build: count + scan + scatter in LDS ----------------
__global__ __launch_bounds__(1024) void build_graph_k(const int* __restrict__ ei, int E,
                                                      int* __restrict__ deg,
                                                      float* __restrict__ dinv,
                                                      int* __restrict__ off,
                                                      int* __restrict__ csr) {
    int g = blockIdx.x, t = threadIdx.x;
    __shared__ int cnt[NPG];               // counts, then cursors
    __shared__ int soff[NPG];              // local start offsets
    __shared__ unsigned short lcsr[EPG];   // src local ids, dst-grouped
    __shared__ int red[1024];
    const int gbase = g * NPG;
    const int ebase = g * EPG;
    const int* __restrict__ srcp = ei + ebase;
    const int* __restrict__ dstp = ei + E + ebase;

    for (int i = t; i < NPG; i += 1024) cnt[i] = 0;
    __syncthreads();
    // phase 1: count in-degree (LDS atomics)
    for (int i = t; i < EPG; i += 1024) atomicAdd(&cnt[dstp[i] - gbase], 1);
    __syncthreads();
    // phase 2: exclusive scan over 1000 counts (1/thread, Hillis-Steele on 1024)
    int v = (t < NPG) ? cnt[t] : 0;
    red[t] = v;
    __syncthreads();
    for (int o = 1; o < 1024; o <<= 1) {
        int xx = (t >= o) ? red[t - o] : 0;
        __syncthreads();
        red[t] += xx;
        __syncthreads();
    }
    if (t < NPG) soff[t] = red[t] - v;     // exclusive prefix
    __syncthreads();
    // outputs: deg, dinv, off (coalesced)
    for (int i = t; i < NPG; i += 1024) {
        int d = cnt[i];
        deg[gbase + i] = d;
        dinv[gbase + i] = 1.0f / sqrtf((float)(d + 1));
        off[gbase + i] = ebase + soff[i];
    }
    __syncthreads();
    // reset cursors
    for (int i = t; i < NPG; i += 1024) cnt[i] = soff[i];
    __syncthreads();
    // phase 3: scatter src into dst-grouped order (LDS cursor atomics + LDS writes)
    for (int i = t; i < EPG; i += 1024) {
        int d = dstp[i] - gbase;
        int pos = atomicAdd(&cnt[d], 1);
        lcsr[pos] = (unsigned short)(srcp[i] - gbase);
    }
    __syncthreads();
    // phase 4: dump csr as coalesced int4 stores (EPG % 4 == 0)
    int4* co = (int4*)(csr + ebase);
    for (int i = t; i < EPG / 4; i += 1024) {
        int4 vv;
        vv.x = gbase + (int)lcsr[i * 4 + 0];
        vv.y = gbase + (int)lcsr[i * 4 + 1];
        vv.z = gbase + (int)lcsr[i * 4 + 2];
        vv.w = gbase + (int)lcsr[i * 4 + 3];
        co[i] = vv;
    }
}

// ---------------- h2 = (x @ W) * dinv[row] : register-tiled, 2 rows/thread, W in LDS --------
__global__ __launch_bounds__(256) void gemm_k(const float* __restrict__ x,
                                              const float* __restrict__ W,
                                              const float* __restrict__ dinv,
                                              float* __restrict__ h2, int N) {
    __shared__ float sW[C * C];
    int t = threadIdx.x;
    for (int i = t; i < C * C / 4; i += 256) ((float4*)sW)[i] = ((const float4*)W)[i];
    __syncthreads();
    int r0 = blockIdx.x * 512 + t;
    int r1 = r0 + 256;
    if (r0 >= N) return;
    bool has1 = (r1 < N);
    const float4* x0 = (const float4*)(x + (size_t)r0 * C);
    const float4* x1 = (const float4*)(x + (size_t)(has1 ? r1 : r0) * C);
    float acc0[C], acc1[C];
#pragma unroll
    for (int i = 0; i < C; ++i) { acc0[i] = 0.f; acc1[i] = 0.f; }
    float4 a0 = x0[0], a1 = x1[0];
    for (int k4 = 0; k4 < 16; ++k4) {
        float4 b0, b1;
        if (k4 < 15) { b0 = x0[k4 + 1]; b1 = x1[k4 + 1]; }
        const float4* wr = (const float4*)(sW + k4 * 4 * C);
        const float* a0f = (const float*)&a0;
        const float* a1f = (const float*)&a1;
#pragma unroll
        for (int c4 = 0; c4 < 16; ++c4) {
            float4 w[4];
            w[0] = wr[c4]; w[1] = wr[16 + c4]; w[2] = wr[32 + c4]; w[3] = wr[48 + c4];
            const float* wf = (const float*)w;
#pragma unroll
            for (int j = 0; j < 4; ++j) {
                float s0 = acc0[c4 * 4 + j], s1 = acc1[c4 * 4 + j];
#pragma unroll
                for (int kk = 0; kk < 4; ++kk) {
                    float wv = wf[kk * 4 + j];
                    s0 = fmaf(a0f[kk], wv, s0);
                    s1 = fmaf(a1f[kk], wv, s1);
                }
                acc0[c4 * 4 + j] = s0; acc1[c4 * 4 + j] = s1;
            }
        }
        a0 = b0; a1 = b1;
    }
    float dv0 = dinv[r0];
    float dv1 = has1 ? dinv[r1] : 0.f;
#pragma unroll
    for (int i = 0; i < C; ++i) { acc0[i] *= dv0; acc1[i] *= dv1; }
    float4* h0 = (float4*)(h2 + (size_t)r0 * C);
#pragma unroll
    for (int q = 0; q < 16; ++q) h0[q] = ((float4*)acc0)[q];
    if (has1) {
        float4* h1 = (float4*)(h2 + (size_t)r1 * C);
#pragma unroll
        for (int q = 0; q < 16; ++q) h1[q] = ((float4*)acc1)[q];
    }
}

// ---------------- gather aggregation: 4 nodes per wave, lane = channel -----------------
// 4 independent gather chains per wave, per-node guarded trip counts (wave-uniform
// branches). Pad slots hold own node id; compensated via coef fold. Per-graph
// centroid partial sums fused: LDS accumulate + 1 global atomic per block.
__global__ __launch_bounds__(256) void gather_k(const int* __restrict__ csr,
                                                const int* __restrict__ off,
                                                const int* __restrict__ deg,
                                                const float* __restrict__ h2,
                                                const float* __restrict__ dinv,
                                                const float* __restrict__ bias,
                                                float* __restrict__ out2,
                                                float* __restrict__ cen_sum,
                                                int N, int B) {
    __shared__ float cenacc[C];
    int blk = blockIdx.x;
    int wave = threadIdx.x >> 6;
    int lane = threadIdx.x & 63;
    int t = threadIdx.x;
    int g, blkin;
    if ((B & 7) == 0) {                    // XCD swizzle: whole graph on one XCD
        int xcd = blk & 7, slot = blk >> 3;
        g = (slot / BPG) * 8 + xcd;
        blkin = slot % BPG;
    } else {
        g = blk / BPG;
        blkin = blk % BPG;
    }
    if (t < C) cenacc[t] = 0.f;
    __syncthreads();

    int base = blkin * 4 + wave;
    bool active = (base < NPG / 4);
    if (active) {
        int nA = g * NPG + base;
        int nB = nA + 250, nC = nA + 500, nD = nA + 750;
        int oA = off[nA], oB = off[nB], oC = off[nC], oD = off[nD];
        int dA = deg[nA], dB = deg[nB], dC = deg[nC], dD = deg[nD];
        float diA = dinv[nA], diB = dinv[nB], diC = dinv[nC], diD = dinv[nD];
        float hA = h2[(size_t)nA * C + lane];
        float hB = h2[(size_t)nB * C + lane];
        float hC = h2[(size_t)nC * C + lane];
        float hD = h2[(size_t)nD * C + lane];
        float bv = bias[lane];
        int svA = (lane < dA) ? csr[oA + lane] : nA;
        int svB = (lane < dB) ? csr[oB + lane] : nB;
        int svC = (lane < dC) ? csr[oC + lane] : nC;
        int svD = (lane < dD) ? csr[oD + lane] : nD;
        int jmA = dA < 64 ? dA : 64;
        int jmB = dB < 64 ? dB : 64;
        int jmC = dC < 64 ? dC : 64;
        int jmD = dD < 64 ? dD : 64;
        int rA = (jmA + 3) & ~3, rB = (jmB + 3) & ~3;
        int rC = (jmC + 3) & ~3, rD = (jmD + 3) & ~3;
        int m0 = rA > rB ? rA : rB;
        int m1 = rC > rD ? rC : rD;
        int mmax = m0 > m1 ? m0 : m1;
        float aA = 0.f, aB = 0.f, aC = 0.f, aD = 0.f;
        for (int j = 0; j < mmax; j += 4) {
            if (j < rA) {
                int s0 = readlane_i(svA, j + 0), s1 = readlane_i(svA, j + 1);
                int s2 = readlane_i(svA, j + 2), s3 = readlane_i(svA, j + 3);
                float v0 = h2[(size_t)s0 * C + lane];
                float v1 = h2[(size_t)s1 * C + lane];
                float v2 = h2[(size_t)s2 * C + lane];
                float v3 = h2[(size_t)s3 * C + lane];
                aA += (v0 + v1) + (v2 + v3);
            }
            if (j < rB) {
                int s0 = readlane_i(svB, j + 0), s1 = readlane_i(svB, j + 1);
                int s2 = readlane_i(svB, j + 2), s3 = readlane_i(svB, j + 3);
                float v0 = h2[(size_t)s0 * C + lane];
                float v1 = h2[(size_t)s1 * C + lane];
                float v2 = h2[(size_t)s2 * C + lane];
                float v3 = h2[(size_t)s3 * C + lane];
                aB += (v0 + v1) + (v2 + v3);
            }
            if (j < rC) {
                int s0 = readlane_i(svC, j + 0), s1 = readlane_i(svC, j + 1);
                int s2 = readlane_i(svC, j + 2), s3 = readlane_i(svC, j + 3);
                float v0 = h2[(size_t)s0 * C + lane];
                float v1 = h2[(size_t)s1 * C + lane];
                float v2 = h2[(size_t)s2 * C + lane];
                float v3 = h2[(size_t)s3 * C + lane];
                aC += (v0 + v1) + (v2 + v3);
            }
            if (j < rD) {
                int s0 = readlane_i(svD, j + 0), s1 = readlane_i(svD, j + 1);
                int s2 = readlane_i(svD, j + 2), s3 = readlane_i(svD, j + 3);
                float v0 = h2[(size_t)s0 * C + lane];
                float v1 = h2[(size_t)s1 * C + lane];
                float v2 = h2[(size_t)s2 * C + lane];
                float v3 = h2[(size_t)s3 * C + lane];
                aD += (v0 + v1) + (v2 + v3);
            }
        }
        for (int j = 64; j < dA; ++j) aA += h2[(size_t)csr[oA + j] * C + lane];
        for (int j = 64; j < dB; ++j) aB += h2[(size_t)csr[oB + j] * C + lane];
        for (int j = 64; j < dC; ++j) aC += h2[(size_t)csr[oC + j] * C + lane];
        for (int j = 64; j < dD; ++j) aD += h2[(size_t)csr[oD + j] * C + lane];
        float cA = 1.0f - (float)(rA - jmA);
        float cB = 1.0f - (float)(rB - jmB);
        float cC = 1.0f - (float)(rC - jmC);
        float cD = 1.0f - (float)(rD - jmD);
        float resA = fmaf(diA, fmaf(cA, hA, aA), bv);
        float resB = fmaf(diB, fmaf(cB, hB, aB), bv);
        float resC = fmaf(diC, fmaf(cC, hC, aC), bv);
        float resD = fmaf(diD, fmaf(cD, hD, aD), bv);
        out2[(size_t)nA * C + lane] = resA;
        out2[(size_t)nB * C + lane] = resB;
        out2[(size_t)nC * C + lane] = resC;
        out2[(size_t)nD * C + lane] = resD;
        float csum = (resA + resB) + (resC + resD);
        atomicAdd(&cenacc[lane], csum);
    }
    __syncthreads();
    if (t < C) atomicAdd(&cen_sum[(size_t)g * C + t], cenacc[t]);
}

// ---------------- centroid finalize: cen + cnorm ----------------
__global__ void cen_fin_k(const float* __restrict__ cen_sum, float* __restrict__ cen,
                          float* __restrict__ cnorm) {
    int g = blockIdx.x, c = threadIdx.x;   // 64 threads
    float m = cen_sum[(size_t)g * C + c] * (1.0f / 1000.0f);
    cen[g * C + c] = m;
    float v = m * m;
    for (int o = 32; o > 0; o >>= 1) v += __shfl_down(v, o, 64);
    if (c == 0) cnorm[g] = sqrtf(v);
}

// ---------------- score: device-wide, wave per 4 rows, lane = channel (coalesced) --------
__global__ __launch_bounds__(256) void score2_k(const float* __restrict__ out2,
                                                const float* __restrict__ cen,
                                                const float* __restrict__ cnorm,
                                                float* __restrict__ score, int N) {
    int wave = threadIdx.x >> 6, lane = threadIdx.x & 63;
    int r0 = blockIdx.x * 16 + wave * 4;          // 4 rows per wave
    if (r0 >= N) return;
    int g0 = r0 / NPG, g1 = (r0 + 1) / NPG, g2 = (r0 + 2) / NPG, g3 = (r0 + 3) / NPG;
    float a0 = out2[(size_t)(r0 + 0) * C + lane];
    float a1 = out2[(size_t)(r0 + 1) * C + lane];
    float a2 = out2[(size_t)(r0 + 2) * C + lane];
    float a3 = out2[(size_t)(r0 + 3) * C + lane];
    float c0 = cen[g0 * C + lane];
    float c1 = cen[g1 * C + lane];
    float c2 = cen[g2 * C + lane];
    float c3 = cen[g3 * C + lane];
    float n0 = a0 * c0, n1 = a1 * c1, n2 = a2 * c2, n3 = a3 * c3;
    float q0 = a0 * a0, q1 = a1 * a1, q2 = a2 * a2, q3 = a3 * a3;
    for (int o = 32; o > 0; o >>= 1) {
        n0 += __shfl_down(n0, o, 64); q0 += __shfl_down(q0, o, 64);
        n1 += __shfl_down(n1, o, 64); q1 += __shfl_down(q1, o, 64);
        n2 += __shfl_down(n2, o, 64); q2 += __shfl_down(q2, o, 64);
        n3 += __shfl_down(n3, o, 64); q3 += __shfl_down(q3, o, 64);
    }
    if (lane == 0) {
        score[r0 + 0] = n0 / (sqrtf(q0) * cnorm[g0] + 1e-8f);
        score[r0 + 1] = n1 / (sqrtf(q1) * cnorm[g1] + 1e-8f);
        score[r0 + 2] = n2 / (sqrtf(q2) * cnorm[g2] + 1e-8f);
        score[r0 + 3] = n3 / (sqrtf(q3) * cnorm[g3] + 1e-8f);
    }
}

// ---------------- per-graph tail: softmax-KL + bitonic argsort + top-K + x_new ----------
__global__ __launch_bounds__(1024) void post2_k(const float* __restrict__ score,
                                                const float* __restrict__ out2,
                                                int* __restrict__ mapping,
                                                float* __restrict__ o_xnew,
                                                float* __restrict__ o_batch,
                                                float* __restrict__ o_perm,
                                                float* __restrict__ o_kl,
                                                float* __restrict__ o_ind) {
    __shared__ float ss[NPG];
    __shared__ float red[1024];
    __shared__ unsigned long long kk[1024];
    __shared__ int   map[NPG];
    int g = blockIdx.x, t = threadIdx.x;
    int wave = t >> 6, lane = t & 63;
    const int gbase = g * NPG;

    // stage score row (coalesced float4)
    const float4* s4 = (const float4*)(score + (size_t)gbase);
    if (t < NPG / 4) ((float4*)ss)[t] = s4[t];
    __syncthreads();
    // softmax KL vs uniform
    float mx = -INFINITY;
    if (t < NPG) mx = ss[t];
    red[t] = mx;
    __syncthreads();
    for (int w = 512; w > 0; w >>= 1) { if (t < w) red[t] = fmaxf(red[t], red[t + w]); __syncthreads(); }
    mx = red[0];
    __syncthreads();
    float se = (t < NPG) ? expf(ss[t] - mx) : 0.f;
    red[t] = se;
    __syncthreads();
    for (int w = 512; w > 0; w >>= 1) { if (t < w) red[t] += red[t + w]; __syncthreads(); }
    float lse = logf(red[0]);
    __syncthreads();
    const float ln_npg = 6.9077552790f;
    float kl = 0.f;
    if (t < NPG) {
        float lp = ss[t] - mx - lse;
        kl = expf(lp) * (lp + ln_npg);
    }
    red[t] = kl;
    __syncthreads();
    for (int w = 512; w > 0; w >>= 1) { if (t < w) red[t] += red[t + w]; __syncthreads(); }
    if (t == 0) o_kl[g] = red[0];
    // descending stable argsort via ascending (~flipped_score, idx) bitonic
    unsigned long long v;
    if (t < NPG) {
        unsigned u = __float_as_uint(ss[t]);
        u = (u & 0x80000000u) ? ~u : (u | 0x80000000u);
        v = ((unsigned long long)(~u) << 32) | (unsigned)t;
    } else {
        v = ~0ULL;
    }
    __syncthreads();
    kk[t] = v;
    __syncthreads();
    for (int k = 2; k <= 1024; k <<= 1) {
        for (int j = k >> 1; j > 0; j >>= 1) {
            int ixj = t ^ j;
            if (ixj > t) {
                unsigned long long a = kk[t], b2 = kk[ixj];
                bool up = ((t & k) == 0);
                if ((a > b2) == up) { kk[t] = b2; kk[ixj] = a; }
            }
            __syncthreads();
        }
    }
    // indices output + mapping init
    if (t < NPG) {
        int idx = (int)(kk[t] & 0xFFFFFFFFULL);
        o_ind[(size_t)g * NPG + t] = (float)idx;
        map[t] = -1;
    }
    __syncthreads();
    // top-K bookkeeping
    if (t < KTOP) {
        int node = (int)(kk[t] & 0xFFFFFFFFULL);
        map[node] = g * KTOP + t;
        o_perm[(size_t)g * KTOP + t] = (float)(gbase + node);
        o_batch[(size_t)g * KTOP + t] = (float)g;
    }
    __syncthreads();
    // mapping -> global (coalesced)
    if (t < NPG) mapping[gbase + t] = map[t];
    // x_new rows: wave per row (coalesced 256B read+write)
    for (int r = wave; r < KTOP; r += 16) {
        int node = (int)(kk[r] & 0xFFFFFFFFULL);
        float tn = tanhf(ss[node]);
        o_xnew[((size_t)g * KTOP + r) * C + lane] =
            out2[(size_t)(gbase + node) * C + lane] * tn;
    }
}

// ---------------- edge re-index + mask + attr (device-wide, x4 vectorized) ----------------
__global__ void edge_out_k(const int* __restrict__ ei, const float* __restrict__ eattr,
                           const int* __restrict__ mapping, float* __restrict__ o_newei,
                           float* __restrict__ o_eattr, float* __restrict__ o_mask, int E) {
    int e4 = blockIdx.x * 256 + threadIdx.x;
    int q = E >> 2;
    if (e4 < q) {
        int4 sidx = ((const int4*)ei)[e4];
        int4 didx = ((const int4*)ei)[q + e4];
        int a0 = mapping[sidx.x], a1 = mapping[sidx.y], a2 = mapping[sidx.z], a3 = mapping[sidx.w];
        int b0 = mapping[didx.x], b1 = mapping[didx.y], b2 = mapping[didx.z], b3 = mapping[didx.w];
        float4 f0 = { (float)a0, (float)a1, (float)a2, (float)a3 };
        float4 f1 = { (float)b0, (float)b1, (float)b2, (float)b3 };
        ((float4*)o_newei)[e4] = f0;
        ((float4*)o_newei)[q + e4] = f1;
        float4 at = ((const float4*)eattr)[e4];
        float4 mk, ea;
        mk.x = (a0 >= 0 && b0 >= 0) ? 1.0f : 0.0f;
        mk.y = (a1 >= 0 && b1 >= 0) ? 1.0f : 0.0f;
        mk.z = (a2 >= 0 && b2 >= 0) ? 1.0f : 0.0f;
        mk.w = (a3 >= 0 && b3 >= 0) ? 1.0f : 0.0f;
        ea.x = mk.x != 0.0f ? at.x : 0.0f;
        ea.y = mk.y != 0.0f ? at.y : 0.0f;
        ea.z = mk.z != 0.0f ? at.z : 0.0f;
        ea.w = mk.w != 0.0f ? at.w : 0.0f;
        ((float4*)o_mask)[e4] = mk;
        ((float4*)o_eattr)[e4] = ea;
    }
}

extern "C" void kernel_launch(void* const* d_in, const int* in_sizes, int n_in,
                              void* d_out, int out_size, void* d_ws, size_t ws_size,
                              hipStream_t stream) {
    (void)n_in; (void)out_size; (void)ws_size;
    const float* x     = (const float*)d_in[1];
    const int*   ei    = (const int*)d_in[2];
    const float* eattr = (const float*)d_in[3];
    const float* W     = (const float*)d_in[5];
    const float* bias  = (const float*)d_in[6];

    const int N  = in_sizes[1] / C;    // 256000
    const int E  = in_sizes[2] / 2;    // 4096000
    const int B  = N / NPG;            // 256
    const int BK = B * KTOP;           // 128000

    // workspace layout
    char* wsp = (char*)d_ws;
    float* out2    = (float*)wsp; wsp += (size_t)N * C * 4;   // 65.5 MB
    float* dinv    = (float*)wsp; wsp += (size_t)N * 4;
    int*   deg     = (int*)wsp;   wsp += (size_t)N * 4;
    int*   off     = (int*)wsp;   wsp += (size_t)N * 4;
    int*   mapping = (int*)wsp;   wsp += (size_t)N * 4;
    float* score   = (float*)wsp; wsp += (size_t)N * 4;
    float* cen_sum = (float*)wsp; wsp += (size_t)B * C * 4;
    float* cen     = (float*)wsp; wsp += (size_t)B * C * 4;
    float* cnorm   = (float*)wsp; wsp += 1024;

    // output layout (flat f32, reference return order)
    float* out     = (float*)d_out;
    float* o_xnew  = out;                                   // BK*C
    float* o_newei = o_xnew + (size_t)BK * C;               // 2E
    float* o_eattr = o_newei + 2 * (size_t)E;               // E
    float* o_mask  = o_eattr + (size_t)E;                   // E
    float* o_batch = o_mask + (size_t)E;                    // BK
    float* o_perm  = o_batch + (size_t)BK;                  // BK
    float* o_kl    = o_perm + (size_t)BK;                   // B
    float* o_ind   = o_kl + (size_t)B;                      // B*NPG

    // scratch aliased onto d_out (dead before those outputs are written)
    float* h2buf = out;                // N*C floats (= o_xnew + o_newei region)
    int*   csr   = (int*)o_eattr;      // E ints

    hipMemsetAsync(cen_sum, 0, (size_t)B * C * 4, stream);

    build_graph_k<<<B, 1024, 0, stream>>>(ei, E, deg, dinv, off, csr);
    gemm_k<<<(N + 511) / 512, 256, 0, stream>>>(x, W, dinv, h2buf, N);
    gather_k<<<B * BPG, 256, 0, stream>>>(csr, off, deg, h2buf, dinv, bias, out2,
                                          cen_sum, N, B);
    cen_fin_k<<<B, 64, 0, stream>>>(cen_sum, cen, cnorm);
    score2_k<<<(N + 15) / 16, 256, 0, stream>>>(out2, cen, cnorm, score, N);
    post2_k<<<B, 1024, 0, stream>>>(score, out2, mapping,
                                    o_xnew, o_batch, o_perm, o_kl, o_ind);
    edge_out_k<<<(E / 4 + 255) / 256, 256, 0, stream>>>(ei, eattr, mapping,
                                                        o_newei, o_eattr, o_mask, E);
}